// Round 1
// baseline (467.967 us; speedup 1.0000x reference)
//
#include <hip/hip_runtime.h>
#include <math.h>

#define D_    2048
#define QH_   32
#define KVH_  8
#define HD_   64
#define B_    2
#define S_    2048
#define NROW_ (B_*S_)     // 4096
#define KVD_  (KVH_*HD_)  // 512

typedef __bf16 bf16;
typedef __bf16 bf16x4 __attribute__((ext_vector_type(4)));
typedef __bf16 bf16x8 __attribute__((ext_vector_type(8)));
typedef float  f32x4  __attribute__((ext_vector_type(4)));

__device__ __forceinline__ f32x4 mfma16(bf16x8 a, bf16x8 b, f32x4 c) {
  return __builtin_amdgcn_mfma_f32_16x16x32_bf16(a, b, c, 0, 0, 0);
}

__device__ __forceinline__ void gload_lds16(const bf16* g, bf16* l) {
  __builtin_amdgcn_global_load_lds(
      (const __attribute__((address_space(1))) void*)g,
      (__attribute__((address_space(3))) void*)l, 16, 0, 0);
}

// ---------------- fp32 -> bf16 convert (x4 vectorized) ----------------
__global__ void k_convert(const float* __restrict__ in, bf16* __restrict__ out, int n4) {
  int i = blockIdx.x * 256 + threadIdx.x;
  if (i >= n4) return;
  f32x4 v = ((const f32x4*)in)[i];
  bf16x4 o;
#pragma unroll
  for (int j = 0; j < 4; j++) o[j] = (bf16)v[j];
  ((bf16x4*)out)[i] = o;
}

// ---------- transpose-convert W[K][N] f32 -> Wt[N][K] bf16 ----------
__global__ void k_transpose_w(const float* __restrict__ W, bf16* __restrict__ Wt,
                              int K, int N) {
  __shared__ float tile[32][33];
  int n0 = blockIdx.x * 32, k0 = blockIdx.y * 32;
  int tx = threadIdx.x, ty = threadIdx.y;  // (32,8)
#pragma unroll
  for (int j = 0; j < 4; j++)
    tile[ty + 8*j][tx] = W[(size_t)(k0 + ty + 8*j) * N + n0 + tx];
  __syncthreads();
#pragma unroll
  for (int j = 0; j < 4; j++)
    Wt[(size_t)(n0 + ty + 8*j) * K + k0 + tx] = (bf16)tile[tx][ty + 8*j];
}

// ---------- Vh[b*s][kv*64+d] -> Vt[(b*8+kv)*64+d][s] (bf16) ----------
__global__ void k_transpose_v(const bf16* __restrict__ Vh, bf16* __restrict__ Vt) {
  __shared__ float tile[32][33];
  int z = blockIdx.z;            // b*8+kv
  int b = z >> 3, kv = z & 7;
  int s0 = blockIdx.x * 32, d0 = blockIdx.y * 32;
  int tx = threadIdx.x, ty = threadIdx.y;
#pragma unroll
  for (int j = 0; j < 4; j++)
    tile[ty + 8*j][tx] = (float)Vh[(size_t)(b*S_ + s0 + ty + 8*j) * KVD_ + kv*HD_ + d0 + tx];
  __syncthreads();
#pragma unroll
  for (int j = 0; j < 4; j++)
    Vt[((size_t)z * HD_ + d0 + ty + 8*j) * S_ + s0 + tx] = (bf16)tile[tx][ty + 8*j];
}

// ---------------- RoPE in-place on Qh and Kh ----------------
// cos[d] == cos[d+32] (emb = concat(freqs,freqs)); pair (d, d+32), d<32.
__global__ void k_rope(bf16* __restrict__ Qh, bf16* __restrict__ Kh) {
  int t = blockIdx.x * 256 + threadIdx.x;      // NROW_*40*32 threads
  int d  = t & 31;
  int hh = (t >> 5) % 40;
  int row = t / 1280;
  if (row >= NROW_) return;
  int s = row & (S_ - 1);
  bf16* p;
  if (hh < QH_) p = Qh + (size_t)row * D_   + hh * HD_;
  else          p = Kh + (size_t)row * KVD_ + (hh - QH_) * HD_;
  // inv_freq = THETA^(-d/32) ; log2(1e6)/32 = 0.62286151
  float invf = exp2f(-(float)d * 0.62286151f);
  float ang = (float)s * invf;
  float sn, cs;
  sincosf(ang, &sn, &cs);
  float x1 = (float)p[d], x2 = (float)p[d + 32];
  p[d]      = (bf16)(x1 * cs - x2 * sn);
  p[d + 32] = (bf16)(x2 * cs + x1 * sn);
}

// ---------------- GEMM: C[M][N] = A[M][K] @ Bt[N][K]^T ----------------
// 128x128 tile, BK=32, 4 waves (2x2), 4x4 frags of 16x16x32 per wave.
// LDS chunk-swizzle: 16B slot ^= (row&3); linear dest + swizzled SOURCE + swizzled read.
template<int OUT_F32_BIAS>
__global__ __launch_bounds__(256) void k_gemm(const bf16* __restrict__ A,
                                              const bf16* __restrict__ Bt,
                                              void* __restrict__ Cout,
                                              const float* __restrict__ bias,
                                              int M, int N, int K) {
  __shared__ alignas(16) bf16 As[128 * 32];
  __shared__ alignas(16) bf16 Bs[128 * 32];
  int tid = threadIdx.x;
  int wave = tid >> 6, lane = tid & 63, hi = lane >> 4, lr = lane & 15;
  int wm = wave >> 1, wn = wave & 1;
  int m0 = blockIdx.y * 128, n0 = blockIdx.x * 128;
  f32x4 acc[4][4] = {};
  int nk = K >> 5;
  for (int kt = 0; kt < nk; kt++) {
    int k0 = kt * 32;
#pragma unroll
    for (int i = 0; i < 2; i++) {
      int c = i * 256 + tid;
      int row = c >> 2, slot = c & 3;
      int dch = slot ^ (row & 3);
      gload_lds16(A  + (size_t)(m0 + row) * K + k0 + dch * 8,
                  As + (i * 256 + wave * 64) * 8);
      gload_lds16(Bt + (size_t)(n0 + row) * K + k0 + dch * 8,
                  Bs + (i * 256 + wave * 64) * 8);
    }
    __syncthreads();
    bf16x8 af[4], bfr[4];
#pragma unroll
    for (int mt = 0; mt < 4; mt++) {
      int row = wm * 64 + mt * 16 + lr;
      int slot = hi ^ (row & 3);
      af[mt] = *(const bf16x8*)(As + row * 32 + slot * 8);
    }
#pragma unroll
    for (int nt = 0; nt < 4; nt++) {
      int row = wn * 64 + nt * 16 + lr;
      int slot = hi ^ (row & 3);
      bfr[nt] = *(const bf16x8*)(Bs + row * 32 + slot * 8);
    }
#pragma unroll
    for (int mt = 0; mt < 4; mt++)
#pragma unroll
      for (int nt = 0; nt < 4; nt++)
        acc[mt][nt] = mfma16(af[mt], bfr[nt], acc[mt][nt]);
    __syncthreads();
  }
  // epilogue: C/D layout col=lane&15, row=4*(lane>>4)+reg  [m89/m91]
#pragma unroll
  for (int mt = 0; mt < 4; mt++)
#pragma unroll
    for (int nt = 0; nt < 4; nt++)
#pragma unroll
      for (int r = 0; r < 4; r++) {
        int grow = m0 + wm * 64 + mt * 16 + 4 * hi + r;
        int gcol = n0 + wn * 64 + nt * 16 + lr;
        float v = acc[mt][nt][r];
        if (OUT_F32_BIAS) ((float*)Cout)[(size_t)grow * N + gcol] = v + bias[gcol];
        else              ((bf16*)Cout)[(size_t)grow * N + gcol] = (bf16)v;
      }
}

// ---------------- Flash attention ----------------
// grid (S/64, QH, B); 256 thr = 4 waves; wave owns 16 q-rows; KVBLK=64.
// K LDS [key][d] & V LDS [d][key], both 128B rows, 16B-chunk slot ^= (row&7).
// P round-trip through per-wave LDS [16][72] (pad -> 2-way banks).
__global__ __launch_bounds__(256) void k_attn(const bf16* __restrict__ Qh,
                                              const bf16* __restrict__ Kh,
                                              const bf16* __restrict__ Vt,
                                              bf16* __restrict__ ctx) {
  __shared__ alignas(16) bf16 Ks[64 * 64];
  __shared__ alignas(16) bf16 Vs[64 * 64];
  __shared__ alignas(16) bf16 Ps[4][16 * 72];
  int tid = threadIdx.x;
  int wave = tid >> 6, lane = tid & 63, hi = lane >> 4, lr = lane & 15;
  int qt = blockIdx.x, h = blockIdx.y, b = blockIdx.z;
  int kv = h & 7;               // jnp.tile -> h % KVH
  int q0 = qt * 64;

  // Q fragments, pre-scaled by 1/sqrt(64)=0.125 (exact in bf16)
  bf16x8 qf[2];
  {
    int qrow = q0 + wave * 16 + lr;
    const bf16* qp = Qh + (size_t)(b * S_ + qrow) * D_ + h * HD_ + hi * 8;
#pragma unroll
    for (int ks = 0; ks < 2; ks++) {
      bf16x8 v = *(const bf16x8*)(qp + ks * 32);
#pragma unroll
      for (int j = 0; j < 8; j++) v[j] = (bf16)((float)v[j] * 0.125f);
      qf[ks] = v;
    }
  }
  float m_run[4], l_run[4];
  f32x4 o[4];
#pragma unroll
  for (int r = 0; r < 4; r++) { m_run[r] = -1e30f; l_run[r] = 0.f; }
#pragma unroll
  for (int nt = 0; nt < 4; nt++) o[nt] = (f32x4){0.f, 0.f, 0.f, 0.f};

  const bf16* Kg = Kh + (size_t)(b * S_) * KVD_ + kv * HD_;          // row stride KVD_
  const bf16* Vg = Vt + (size_t)(b * KVH_ + kv) * HD_ * S_;          // row stride S_

  for (int kt = 0; kt < S_ / 64; kt++) {
    // stage K (64 keys x 64 d) and V^T (64 d x 64 keys): 8 chunks/row
#pragma unroll
    for (int i = 0; i < 2; i++) {
      int c = i * 256 + tid;
      int row = c >> 3, slot = c & 7;
      int dch = slot ^ (row & 7);
      gload_lds16(Kg + (size_t)(kt * 64 + row) * KVD_ + dch * 8,
                  Ks + (i * 256 + wave * 64) * 8);
      gload_lds16(Vg + (size_t)row * S_ + kt * 64 + dch * 8,
                  Vs + (i * 256 + wave * 64) * 8);
    }
    __syncthreads();

    // QK^T: sc[nt] covers keys nt*16..nt*16+15 for this wave's 16 q-rows
    f32x4 sc[4];
#pragma unroll
    for (int nt = 0; nt < 4; nt++) sc[nt] = (f32x4){0.f, 0.f, 0.f, 0.f};
#pragma unroll
    for (int ks = 0; ks < 2; ks++)
#pragma unroll
      for (int nt = 0; nt < 4; nt++) {
        int key = nt * 16 + lr;
        int slot = (ks * 4 + hi) ^ (key & 7);
        bf16x8 kf = *(const bf16x8*)(Ks + key * 64 + slot * 8);
        sc[nt] = mfma16(qf[ks], kf, sc[nt]);
      }

    // online softmax (rows r=0..3 of this lane: q-local = 4*hi+r)
    float alpha[4];
#pragma unroll
    for (int r = 0; r < 4; r++) {
      float mx = fmaxf(fmaxf(sc[0][r], sc[1][r]), fmaxf(sc[2][r], sc[3][r]));
#pragma unroll
      for (int m = 1; m < 16; m <<= 1) mx = fmaxf(mx, __shfl_xor(mx, m, 64));
      float mnew = fmaxf(m_run[r], mx);
      alpha[r] = __expf(m_run[r] - mnew);
      float rs = 0.f;
#pragma unroll
      for (int nt = 0; nt < 4; nt++) {
        float p = __expf(sc[nt][r] - mnew);
        sc[nt][r] = p;
        rs += p;
      }
#pragma unroll
      for (int m = 1; m < 16; m <<= 1) rs += __shfl_xor(rs, m, 64);
      l_run[r] = l_run[r] * alpha[r] + rs;
      m_run[r] = mnew;
    }
#pragma unroll
    for (int nt = 0; nt < 4; nt++)
#pragma unroll
      for (int r = 0; r < 4; r++) o[nt][r] *= alpha[r];

    // P -> per-wave LDS [16][72]
    bf16* P = &Ps[wave][0];
#pragma unroll
    for (int r = 0; r < 4; r++) {
      int q = 4 * hi + r;
#pragma unroll
      for (int nt = 0; nt < 4; nt++)
        P[q * 72 + nt * 16 + lr] = (bf16)sc[nt][r];
    }

    // PV: o[nt] covers d = nt*16..+15
#pragma unroll
    for (int ks = 0; ks < 2; ks++) {
      bf16x8 pf = *(const bf16x8*)(P + lr * 72 + (ks * 4 + hi) * 8);
#pragma unroll
      for (int nt = 0; nt < 4; nt++) {
        int d = nt * 16 + lr;
        int slot = (ks * 4 + hi) ^ (d & 7);
        bf16x8 vf = *(const bf16x8*)(Vs + d * 64 + slot * 8);
        o[nt] = mfma16(pf, vf, o[nt]);
      }
    }
    __syncthreads();
  }

  // normalize + write ctx[b*S+q][h*64+d] bf16
#pragma unroll
  for (int r = 0; r < 4; r++) {
    float inv = 1.f / l_run[r];
    int grow = b * S_ + q0 + wave * 16 + 4 * hi + r;
#pragma unroll
    for (int nt = 0; nt < 4; nt++)
      ctx[(size_t)grow * D_ + h * HD_ + nt * 16 + lr] = (bf16)(o[nt][r] * inv);
  }
}

// ---------------- host ----------------
extern "C" void kernel_launch(void* const* d_in, const int* in_sizes, int n_in,
                              void* d_out, int out_size, void* d_ws, size_t ws_size,
                              hipStream_t stream) {
  const float* q  = (const float*)d_in[0];
  const float* k  = (const float*)d_in[1];
  const float* v  = (const float*)d_in[2];
  // d_in[3] attn_mask: all-ones, unused by the reference
  const float* Wq = (const float*)d_in[4];
  const float* Wk = (const float*)d_in[5];
  const float* Wv = (const float*)d_in[6];
  const float* Wo = (const float*)d_in[7];
  const float* bo = (const float*)d_in[8];

  char* ws = (char*)d_ws;
  // bump layout (68 MB peak, slots reused across the sequenced stages)
  bf16* Abuf = (bf16*)(ws + 0);          // 16.8 MB: bf16 of q / k / v (reused)
  bf16* Wt   = (bf16*)(ws + 16777216);   //  8.4 MB: transposed weight (reused)
  bf16* Qh   = (bf16*)(ws + 25165824);   // 16.8 MB
  bf16* Kh   = (bf16*)(ws + 41943040);   //  4.2 MB
  bf16* Vh   = (bf16*)(ws + 46137344);   //  4.2 MB
  bf16* Vtr  = (bf16*)(ws + 50331648);   //  4.2 MB
  bf16* ctx  = (bf16*)(ws + 54525952);   // 16.8 MB  (end: 71,303,168 B)

  const int n4 = NROW_ * D_ / 4;  // 2,097,152

  // Q path
  k_convert<<<n4 / 256, 256, 0, stream>>>(q, Abuf, n4);
  k_transpose_w<<<dim3(D_/32, D_/32), dim3(32, 8), 0, stream>>>(Wq, Wt, D_, D_);
  k_gemm<0><<<dim3(D_/128, NROW_/128), 256, 0, stream>>>(Abuf, Wt, Qh, nullptr, NROW_, D_, D_);
  // K path
  k_convert<<<n4 / 256, 256, 0, stream>>>(k, Abuf, n4);
  k_transpose_w<<<dim3(KVD_/32, D_/32), dim3(32, 8), 0, stream>>>(Wk, Wt, D_, KVD_);
  k_gemm<0><<<dim3(KVD_/128, NROW_/128), 256, 0, stream>>>(Abuf, Wt, Kh, nullptr, NROW_, KVD_, D_);
  // V path
  k_convert<<<n4 / 256, 256, 0, stream>>>(v, Abuf, n4);
  k_transpose_w<<<dim3(KVD_/32, D_/32), dim3(32, 8), 0, stream>>>(Wv, Wt, D_, KVD_);
  k_gemm<0><<<dim3(KVD_/128, NROW_/128), 256, 0, stream>>>(Abuf, Wt, Vh, nullptr, NROW_, KVD_, D_);
  // RoPE on Qh, Kh
  k_rope<<<(NROW_ * 40 * 32) / 256, 256, 0, stream>>>(Qh, Kh);
  // V transpose to [d][s]
  k_transpose_v<<<dim3(S_/32, HD_/32, B_*KVH_), dim3(32, 8), 0, stream>>>(Vh, Vtr);
  // attention
  k_attn<<<dim3(S_/64, QH_, B_), 256, 0, stream>>>(Qh, Kh, Vtr, ctx);
  // output projection (+bias, fp32 out)
  k_transpose_w<<<dim3(D_/32, D_/32), dim3(32, 8), 0, stream>>>(Wo, Wt, D_, D_);
  k_gemm<1><<<dim3(D_/128, NROW_/128), 256, 0, stream>>>(ctx, Wt, (float*)d_out, bo, NROW_, D_, D_);
}

// Round 2
// 351.021 us; speedup vs baseline: 1.3332x; 1.3332x over previous
//
#include <hip/hip_runtime.h>
#include <math.h>

#define D_    2048
#define QH_   32
#define KVH_  8
#define HD_   64
#define B_    2
#define S_    2048
#define NROW_ (B_*S_)     // 4096
#define KVD_  (KVH_*HD_)  // 512
#define LOG2E 1.44269504f

typedef __bf16 bf16;
typedef __bf16 bf16x2 __attribute__((ext_vector_type(2)));
typedef __bf16 bf16x4 __attribute__((ext_vector_type(4)));
typedef __bf16 bf16x8 __attribute__((ext_vector_type(8)));
typedef float  f32x4  __attribute__((ext_vector_type(4)));
typedef float  f32x16 __attribute__((ext_vector_type(16)));

__device__ __forceinline__ f32x4 mfma16(bf16x8 a, bf16x8 b, f32x4 c) {
  return __builtin_amdgcn_mfma_f32_16x16x32_bf16(a, b, c, 0, 0, 0);
}
__device__ __forceinline__ f32x16 mfma32(bf16x8 a, bf16x8 b, f32x16 c) {
  return __builtin_amdgcn_mfma_f32_32x32x16_bf16(a, b, c, 0, 0, 0);
}

__device__ __forceinline__ void gload_lds16(const bf16* g, bf16* l) {
  __builtin_amdgcn_global_load_lds(
      (const __attribute__((address_space(1))) void*)g,
      (__attribute__((address_space(3))) void*)l, 16, 0, 0);
}

__device__ __forceinline__ unsigned pack_bf16(float a, float b) {
  union { bf16x2 v; unsigned u; } t;
  t.v[0] = (bf16)a; t.v[1] = (bf16)b;
  return t.u;
}

// ---------------- fp32 -> bf16 convert (x4 vectorized) ----------------
__global__ void k_convert(const float* __restrict__ in, bf16* __restrict__ out, int n4) {
  int i = blockIdx.x * 256 + threadIdx.x;
  if (i >= n4) return;
  f32x4 v = ((const f32x4*)in)[i];
  bf16x4 o;
#pragma unroll
  for (int j = 0; j < 4; j++) o[j] = (bf16)v[j];
  ((bf16x4*)out)[i] = o;
}

// ---------- transpose-convert W[K][N] f32 -> Wt[N][K] bf16 ----------
__global__ void k_transpose_w(const float* __restrict__ W, bf16* __restrict__ Wt,
                              int K, int N) {
  __shared__ float tile[32][33];
  int n0 = blockIdx.x * 32, k0 = blockIdx.y * 32;
  int tx = threadIdx.x, ty = threadIdx.y;  // (32,8)
#pragma unroll
  for (int j = 0; j < 4; j++)
    tile[ty + 8*j][tx] = W[(size_t)(k0 + ty + 8*j) * N + n0 + tx];
  __syncthreads();
#pragma unroll
  for (int j = 0; j < 4; j++)
    Wt[(size_t)(n0 + ty + 8*j) * K + k0 + tx] = (bf16)tile[tx][ty + 8*j];
}

// ---------- Vh[b*s][kv*64+d] -> Vt[(b*8+kv)*64+d][s] (bf16) ----------
__global__ void k_transpose_v(const bf16* __restrict__ Vh, bf16* __restrict__ Vt) {
  __shared__ float tile[32][33];
  int z = blockIdx.z;            // b*8+kv
  int b = z >> 3, kv = z & 7;
  int s0 = blockIdx.x * 32, d0 = blockIdx.y * 32;
  int tx = threadIdx.x, ty = threadIdx.y;
#pragma unroll
  for (int j = 0; j < 4; j++)
    tile[ty + 8*j][tx] = (float)Vh[(size_t)(b*S_ + s0 + ty + 8*j) * KVD_ + kv*HD_ + d0 + tx];
  __syncthreads();
#pragma unroll
  for (int j = 0; j < 4; j++)
    Vt[((size_t)z * HD_ + d0 + ty + 8*j) * S_ + s0 + tx] = (bf16)tile[tx][ty + 8*j];
}

// ---------------- RoPE in-place on Qh and Kh ----------------
__global__ void k_rope(bf16* __restrict__ Qh, bf16* __restrict__ Kh) {
  int t = blockIdx.x * 256 + threadIdx.x;      // NROW_*40*32 threads
  int d  = t & 31;
  int hh = (t >> 5) % 40;
  int row = t / 1280;
  if (row >= NROW_) return;
  int s = row & (S_ - 1);
  bf16* p;
  if (hh < QH_) p = Qh + (size_t)row * D_   + hh * HD_;
  else          p = Kh + (size_t)row * KVD_ + (hh - QH_) * HD_;
  float invf = exp2f(-(float)d * 0.62286151f);
  float ang = (float)s * invf;
  float sn, cs;
  sincosf(ang, &sn, &cs);
  float x1 = (float)p[d], x2 = (float)p[d + 32];
  p[d]      = (bf16)(x1 * cs - x2 * sn);
  p[d + 32] = (bf16)(x2 * cs + x1 * sn);
}

// ---------------- GEMM: C[M][N] = A[M][K] @ Bt[N][K]^T ----------------
template<int OUT_F32_BIAS>
__global__ __launch_bounds__(256) void k_gemm(const bf16* __restrict__ A,
                                              const bf16* __restrict__ Bt,
                                              void* __restrict__ Cout,
                                              const float* __restrict__ bias,
                                              int M, int N, int K) {
  __shared__ alignas(16) bf16 As[128 * 32];
  __shared__ alignas(16) bf16 Bs[128 * 32];
  int tid = threadIdx.x;
  int wave = tid >> 6, lane = tid & 63, hi = lane >> 4, lr = lane & 15;
  int wm = wave >> 1, wn = wave & 1;
  int m0 = blockIdx.y * 128, n0 = blockIdx.x * 128;
  f32x4 acc[4][4] = {};
  int nk = K >> 5;
  for (int kt = 0; kt < nk; kt++) {
    int k0 = kt * 32;
#pragma unroll
    for (int i = 0; i < 2; i++) {
      int c = i * 256 + tid;
      int row = c >> 2, slot = c & 3;
      int dch = slot ^ (row & 3);
      gload_lds16(A  + (size_t)(m0 + row) * K + k0 + dch * 8,
                  As + (i * 256 + wave * 64) * 8);
      gload_lds16(Bt + (size_t)(n0 + row) * K + k0 + dch * 8,
                  Bs + (i * 256 + wave * 64) * 8);
    }
    __syncthreads();
    bf16x8 af[4], bfr[4];
#pragma unroll
    for (int mt = 0; mt < 4; mt++) {
      int row = wm * 64 + mt * 16 + lr;
      int slot = hi ^ (row & 3);
      af[mt] = *(const bf16x8*)(As + row * 32 + slot * 8);
    }
#pragma unroll
    for (int nt = 0; nt < 4; nt++) {
      int row = wn * 64 + nt * 16 + lr;
      int slot = hi ^ (row & 3);
      bfr[nt] = *(const bf16x8*)(Bs + row * 32 + slot * 8);
    }
#pragma unroll
    for (int mt = 0; mt < 4; mt++)
#pragma unroll
      for (int nt = 0; nt < 4; nt++)
        acc[mt][nt] = mfma16(af[mt], bfr[nt], acc[mt][nt]);
    __syncthreads();
  }
#pragma unroll
  for (int mt = 0; mt < 4; mt++)
#pragma unroll
    for (int nt = 0; nt < 4; nt++)
#pragma unroll
      for (int r = 0; r < 4; r++) {
        int grow = m0 + wm * 64 + mt * 16 + 4 * hi + r;
        int gcol = n0 + wn * 64 + nt * 16 + lr;
        float v = acc[mt][nt][r];
        if (OUT_F32_BIAS) ((float*)Cout)[(size_t)grow * N + gcol] = v + bias[gcol];
        else              ((bf16*)Cout)[(size_t)grow * N + gcol] = (bf16)v;
      }
}

// ---------------- Flash attention v2: swapped QK^T, 32x32 MFMA ----------------
// grid (S/128, QH, B); 256 thr = 4 waves; wave owns 32 q-rows; KVBLK=64.
// Swapped QK: D[key][q], q = lane&31 -> softmax lane-local (1 shfl per reduce).
// P -> PV A-frags via bf16 pack + v_permlane32_swap (no LDS round-trip).
// K LDS [key][d], V LDS [d][key]; 16B-chunk slot ^= (row&7).
__global__ __launch_bounds__(256) void k_attn(const bf16* __restrict__ Qh,
                                              const bf16* __restrict__ Kh,
                                              const bf16* __restrict__ Vt,
                                              bf16* __restrict__ ctx) {
  __shared__ alignas(16) bf16 Ks[64 * 64];
  __shared__ alignas(16) bf16 Vs[64 * 64];
  int tid = threadIdx.x;
  int wave = tid >> 6, lane = tid & 63, hi2 = lane >> 5, l31 = lane & 31;
  int qt = blockIdx.x, h = blockIdx.y, b = blockIdx.z;
  int kv = h & 7;
  int q0 = qt * 128 + wave * 32;      // this wave's q-base

  // Q B-frags from global: lane holds Q[q0+l31][hi2*8 + 16*df + j], scaled 0.125 (exact)
  bf16x8 qf[4];
  {
    const bf16* qp = Qh + (size_t)(b * S_ + q0 + l31) * D_ + h * HD_ + hi2 * 8;
#pragma unroll
    for (int df = 0; df < 4; df++) {
      bf16x8 v = *(const bf16x8*)(qp + 16 * df);
#pragma unroll
      for (int j = 0; j < 8; j++) v[j] = (bf16)((float)v[j] * 0.125f);
      qf[df] = v;
    }
  }

  float m_run = -1e30f, l_run = 0.f;
  f32x16 o0, o1;
#pragma unroll
  for (int i = 0; i < 16; i++) { o0[i] = 0.f; o1[i] = 0.f; }

  const bf16* Kg = Kh + (size_t)(b * S_) * KVD_ + kv * HD_;
  const bf16* Vg = Vt + (size_t)(b * KVH_ + kv) * HD_ * S_;

  for (int kt = 0; kt < S_ / 64; kt++) {
    // ---- stage K[64key][64d] and V^T[64d][64key]; chunk slot ^= row&7 ----
#pragma unroll
    for (int i = 0; i < 2; i++) {
      int c = i * 256 + tid;
      int row = c >> 3, slot = c & 7;
      int dch = slot ^ (row & 7);
      gload_lds16(Kg + (size_t)(kt * 64 + row) * KVD_ + dch * 8,
                  Ks + (i * 256 + wave * 64) * 8);
      gload_lds16(Vg + (size_t)row * S_ + kt * 64 + dch * 8,
                  Vs + (i * 256 + wave * 64) * 8);
    }
    __syncthreads();

    // ---- QK^T (swapped): s0 = keys 0..31, s1 = keys 32..63; col q = l31 ----
    f32x16 s0, s1;
#pragma unroll
    for (int i = 0; i < 16; i++) { s0[i] = 0.f; s1[i] = 0.f; }
#pragma unroll
    for (int df = 0; df < 4; df++) {
      int ch = hi2 + 2 * df;
      int sl = (ch ^ (l31 & 7)) << 3;
      bf16x8 k0 = *(const bf16x8*)(Ks + l31 * 64 + sl);
      bf16x8 k1 = *(const bf16x8*)(Ks + (l31 + 32) * 64 + sl);
      s0 = mfma32(k0, qf[df], s0);
      s1 = mfma32(k1, qf[df], s1);
    }

    // ---- online softmax, lane-local (q = l31) ----
    float mx = s0[0];
#pragma unroll
    for (int i = 1; i < 16; i++) mx = fmaxf(mx, s0[i]);
#pragma unroll
    for (int i = 0; i < 16; i++) mx = fmaxf(mx, s1[i]);
    mx = fmaxf(mx, __shfl_xor(mx, 32, 64));

    if (__any(mx > m_run + 5.545f)) {   // defer-max: p bounded by 2^8
      float mnew = fmaxf(m_run, mx);
      float alpha = __builtin_amdgcn_exp2f((m_run - mnew) * LOG2E);
      l_run *= alpha;
      m_run = mnew;
#pragma unroll
      for (int r = 0; r < 16; r++) {
        float ar = __shfl(alpha, (r & 3) + 8 * (r >> 2) + 4 * hi2, 64);
        o0[r] *= ar; o1[r] *= ar;
      }
    }
    float mexp = m_run * LOG2E;
    float rs = 0.f;
#pragma unroll
    for (int i = 0; i < 16; i++) {
      s0[i] = __builtin_amdgcn_exp2f(fmaf(s0[i], LOG2E, -mexp));
      rs += s0[i];
    }
#pragma unroll
    for (int i = 0; i < 16; i++) {
      s1[i] = __builtin_amdgcn_exp2f(fmaf(s1[i], LOG2E, -mexp));
      rs += s1[i];
    }
    rs += __shfl_xor(rs, 32, 64);
    l_run += rs;

    // ---- pack P to bf16 dwords: Rk[kf][m][w] = keys kf*32+8m+4*hi2 + {2w,2w+1} ----
    unsigned Rk[2][4][2];
#pragma unroll
    for (int m = 0; m < 4; m++)
#pragma unroll
      for (int w = 0; w < 2; w++) {
        Rk[0][m][w] = pack_bf16(s0[4*m + 2*w], s0[4*m + 2*w + 1]);
        Rk[1][m][w] = pack_bf16(s1[4*m + 2*w], s1[4*m + 2*w + 1]);
      }
    // ---- half-wave exchange: vdst[32:63] <-> vsrc[0:31] ----
#pragma unroll
    for (int kf = 0; kf < 2; kf++)
#pragma unroll
      for (int kp = 0; kp < 2; kp++)
#pragma unroll
        for (int w = 0; w < 2; w++)
          asm volatile("v_permlane32_swap_b32 %0, %1"
                       : "+v"(Rk[kf][2*kp][w]), "+v"(Rk[kf][2*kp+1][w]));
    // ---- assemble PV A-frags: keys 16*kfr + 8*hi2 + j ----
    bf16x8 pf[4];
#pragma unroll
    for (int kfr = 0; kfr < 4; kfr++) {
      int kf = kfr >> 1, k2 = (kfr & 1) * 2;
      union { unsigned d[4]; bf16x8 v; } u;
      u.d[0] = Rk[kf][k2][0];     u.d[1] = Rk[kf][k2][1];
      u.d[2] = Rk[kf][k2 + 1][0]; u.d[3] = Rk[kf][k2 + 1][1];
      pf[kfr] = u.v;
    }

    // ---- PV: o[dv] cols d = l31 + 32*dv ----
#pragma unroll
    for (int kfr = 0; kfr < 4; kfr++) {
      int ch = hi2 + 2 * kfr;
      int sl = (ch ^ (l31 & 7)) << 3;
      bf16x8 v0 = *(const bf16x8*)(Vs + l31 * 64 + sl);
      bf16x8 v1 = *(const bf16x8*)(Vs + (l31 + 32) * 64 + sl);
      o0 = mfma32(pf[kfr], v0, o0);
      o1 = mfma32(pf[kfr], v1, o1);
    }
    __syncthreads();
  }

  // ---- normalize and write: row q = (r&3)+8*(r>>2)+4*hi2, col d = l31+32*dv ----
#pragma unroll
  for (int r = 0; r < 16; r++) {
    int rowq = (r & 3) + 8 * (r >> 2) + 4 * hi2;
    float li = __shfl(l_run, rowq, 64);
    float inv = 1.f / li;
    size_t base = (size_t)(b * S_ + q0 + rowq) * D_ + h * HD_;
    ctx[base + l31]      = (bf16)(o0[r] * inv);
    ctx[base + l31 + 32] = (bf16)(o1[r] * inv);
  }
}

// ---------------- host ----------------
extern "C" void kernel_launch(void* const* d_in, const int* in_sizes, int n_in,
                              void* d_out, int out_size, void* d_ws, size_t ws_size,
                              hipStream_t stream) {
  const float* q  = (const float*)d_in[0];
  const float* k  = (const float*)d_in[1];
  const float* v  = (const float*)d_in[2];
  const float* Wq = (const float*)d_in[4];
  const float* Wk = (const float*)d_in[5];
  const float* Wv = (const float*)d_in[6];
  const float* Wo = (const float*)d_in[7];
  const float* bo = (const float*)d_in[8];

  char* ws = (char*)d_ws;
  bf16* Abuf = (bf16*)(ws + 0);
  bf16* Wt   = (bf16*)(ws + 16777216);
  bf16* Qh   = (bf16*)(ws + 25165824);
  bf16* Kh   = (bf16*)(ws + 41943040);
  bf16* Vh   = (bf16*)(ws + 46137344);
  bf16* Vtr  = (bf16*)(ws + 50331648);
  bf16* ctx  = (bf16*)(ws + 54525952);

  const int n4 = NROW_ * D_ / 4;

  k_convert<<<n4 / 256, 256, 0, stream>>>(q, Abuf, n4);
  k_transpose_w<<<dim3(D_/32, D_/32), dim3(32, 8), 0, stream>>>(Wq, Wt, D_, D_);
  k_gemm<0><<<dim3(D_/128, NROW_/128), 256, 0, stream>>>(Abuf, Wt, Qh, nullptr, NROW_, D_, D_);
  k_convert<<<n4 / 256, 256, 0, stream>>>(k, Abuf, n4);
  k_transpose_w<<<dim3(KVD_/32, D_/32), dim3(32, 8), 0, stream>>>(Wk, Wt, D_, KVD_);
  k_gemm<0><<<dim3(KVD_/128, NROW_/128), 256, 0, stream>>>(Abuf, Wt, Kh, nullptr, NROW_, KVD_, D_);
  k_convert<<<n4 / 256, 256, 0, stream>>>(v, Abuf, n4);
  k_transpose_w<<<dim3(KVD_/32, D_/32), dim3(32, 8), 0, stream>>>(Wv, Wt, D_, KVD_);
  k_gemm<0><<<dim3(KVD_/128, NROW_/128), 256, 0, stream>>>(Abuf, Wt, Vh, nullptr, NROW_, KVD_, D_);
  k_rope<<<(NROW_ * 40 * 32) / 256, 256, 0, stream>>>(Qh, Kh);
  k_transpose_v<<<dim3(S_/32, HD_/32, B_*KVH_), dim3(32, 8), 0, stream>>>(Vh, Vtr);
  k_attn<<<dim3(S_/128, QH_, B_), 256, 0, stream>>>(Qh, Kh, Vtr, ctx);
  k_transpose_w<<<dim3(D_/32, D_/32), dim3(32, 8), 0, stream>>>(Wo, Wt, D_, D_);
  k_gemm<1><<<dim3(D_/128, NROW_/128), 256, 0, stream>>>(ctx, Wt, (float*)d_out, bo, NROW_, D_, D_);
}